// Round 5
// baseline (10906.837 us; speedup 1.0000x reference)
//
#include <hip/hip_runtime.h>
#include <hip/hip_bf16.h>
#include <stdint.h>

#define HW      64
#define CIN     512
#define KOUT    512
#define BATCH   8
#define NANCH   9
#define NBOX    (HW*HW*NANCH)   /* 36864 */
#define PRE_NMS 6000
#define POST_NMS 300
#define SORT_N  8192

// ---------------------------------------------------------------------------
// Kernel 1: 3x3 conv (pad=1) + bias + ReLU.  fp32 vector-FMA implicit GEMM.
// WG tile: 4 rows x 64 cols x 64 out-channels.  Per-thread: 2x4 px x 8 ch.
// Per-output accumulation order (ci-major, tap-minor, serial fp32 fmaf) is
// BIT-IDENTICAL to the round-1 passing kernel.  Changes vs R1 are staging
// layout (conflict-free) and occupancy only.
// ---------------------------------------------------------------------------
__global__ __launch_bounds__(256, 4)
void conv3x3_relu(const float* __restrict__ in, const float* __restrict__ w,
                  const float* __restrict__ bias, float* __restrict__ feat) {
    __shared__ float s_in[8][6][66];   // 8 c, rows y0-1..y0+4, cols -1..64
    __shared__ float s_w2[64 * 73];    // [k][ci*9+tap], row stride 73 (pad)

    const int tid = threadIdx.x;
    const int k0  = blockIdx.x * 64;
    const int y0  = blockIdx.y * 4;
    const int b   = blockIdx.z;
    const int kg  = tid & 7;          // 8 channel groups of 8
    const int pos = tid >> 3;         // 0..31
    const int tx  = pos & 15;         // x0 = tx*4
    const int ty  = pos >> 4;         // rows ty*2, ty*2+1
    const int x0  = tx * 4;

    float acc[2][8][4];
#pragma unroll
    for (int r = 0; r < 2; ++r)
#pragma unroll
        for (int k = 0; k < 8; ++k)
#pragma unroll
            for (int c = 0; c < 4; ++c) acc[r][k][c] = 0.0f;

    for (int cc = 0; cc < CIN; cc += 8) {
        __syncthreads();
        // stage input (zero-padded halo) — write pattern contiguous, conflict-free
        for (int i = tid; i < 8 * 6 * 66; i += 256) {
            int ci = i / 396; int rem = i % 396;
            int r = rem / 66; int col = rem % 66;
            int gx = col - 1; int gy = y0 - 1 + r;
            float v = 0.0f;
            if ((unsigned)gx < 64u && (unsigned)gy < 64u)
                v = in[(((size_t)b * CIN + cc + ci) * HW + gy) * HW + gx];
            s_in[ci][r][col] = v;
        }
        // stage weights: per k the 72 floats (ci*9+tap) are contiguous in
        // global AND in LDS -> coalesced reads, conflict-free writes.
        for (int i = tid; i < 64 * 72; i += 256) {
            int k = i / 72; int j = i % 72;
            s_w2[k * 73 + j] = w[(size_t)(k0 + k) * (CIN * 9) + cc * 9 + j];
        }
        __syncthreads();

#pragma unroll
        for (int ci = 0; ci < 8; ++ci) {
#pragma unroll
            for (int dy = 0; dy < 3; ++dy) {
                float iv[2][6];
#pragma unroll
                for (int rr = 0; rr < 2; ++rr) {
                    int r = ty * 2 + rr + dy;
#pragma unroll
                    for (int c = 0; c < 6; ++c) iv[rr][c] = s_in[ci][r][x0 + c];
                }
#pragma unroll
                for (int dx = 0; dx < 3; ++dx) {
                    float wv[8];
#pragma unroll
                    for (int kk = 0; kk < 8; ++kk)
                        wv[kk] = s_w2[(kg * 8 + kk) * 73 + ci * 9 + dy * 3 + dx];
#pragma unroll
                    for (int rr = 0; rr < 2; ++rr)
#pragma unroll
                        for (int k = 0; k < 8; ++k)
#pragma unroll
                            for (int c = 0; c < 4; ++c)
                                acc[rr][k][c] = fmaf(iv[rr][dx + c], wv[k], acc[rr][k][c]);
                }
            }
        }
    }
    // bias + relu + store (float4 over x) — identical to R1
#pragma unroll
    for (int k = 0; k < 8; ++k) {
        float bv = bias[k0 + kg * 8 + k];
#pragma unroll
        for (int rr = 0; rr < 2; ++rr) {
            int y = y0 + ty * 2 + rr;
            float4 o;
            o.x = fmaxf(acc[rr][k][0] + bv, 0.0f);
            o.y = fmaxf(acc[rr][k][1] + bv, 0.0f);
            o.z = fmaxf(acc[rr][k][2] + bv, 0.0f);
            o.w = fmaxf(acc[rr][k][3] + bv, 0.0f);
            *(float4*)&feat[(((size_t)b * KOUT + k0 + kg * 8 + k) * HW + y) * HW + x0] = o;
        }
    }
}

// ---------------------------------------------------------------------------
// Kernel 2: 1x1 cls+reg heads fused with softmax, box decode, clip, min-size
// filter and sortable-key packing.  One thread per pixel.  (R1 verbatim)
// ---------------------------------------------------------------------------
__global__ __launch_bounds__(256, 2)
void heads(const float* __restrict__ feat,
           const float* __restrict__ wcls, const float* __restrict__ bcls,
           const float* __restrict__ wreg, const float* __restrict__ breg,
           const float* __restrict__ iminfo,
           unsigned long long* __restrict__ keys, float4* __restrict__ pbox) {
    __shared__ float s_w[128 * 56];   // [c][j] j=0..53 (18 cls + 36 reg), pad 56

    const int tid = threadIdx.x;
    const int pix = blockIdx.x * 256 + tid;
    const int b   = pix >> 12;
    const int rem = pix & 4095;
    const int y   = rem >> 6;
    const int x   = rem & 63;

    float acc[54];
#pragma unroll
    for (int j = 0; j < 54; ++j) acc[j] = 0.0f;

    for (int cc = 0; cc < 512; cc += 128) {
        __syncthreads();
        for (int i = tid; i < 128 * 54; i += 256) {
            int j = i / 128; int cl = i % 128;
            float v = (j < 18) ? wcls[(size_t)j * 512 + cc + cl]
                               : wreg[(size_t)(j - 18) * 512 + cc + cl];
            s_w[cl * 56 + j] = v;
        }
        __syncthreads();
        for (int c2 = 0; c2 < 128; ++c2) {
            float f = feat[(((size_t)b * 512 + cc + c2) * 64 + y) * 64 + x];
#pragma unroll
            for (int j = 0; j < 54; ++j)
                acc[j] = fmaf(f, s_w[c2 * 56 + j], acc[j]);
        }
    }

    const float im_h = iminfo[b * 3 + 0];
    const float im_w = iminfo[b * 3 + 1];
    const float ms   = 16.0f * iminfo[b * 3 + 2];
    const float ASP[3] = {0.5f, 1.0f, 2.0f};
    const float SCL[3] = {8.0f, 16.0f, 32.0f};

#pragma unroll
    for (int a = 0; a < 9; ++a) {
        float c0 = acc[2 * a]     + bcls[2 * a];
        float c1 = acc[2 * a + 1] + bcls[2 * a + 1];
        float m  = fmaxf(c0, c1);
        float e0 = expf(c0 - m), e1 = expf(c1 - m);
        float fg = e1 / (e0 + e1);

        float d0 = acc[18 + 4 * a + 0] + breg[4 * a + 0];
        float d1 = acc[18 + 4 * a + 1] + breg[4 * a + 1];
        float d2 = acc[18 + 4 * a + 2] + breg[4 * a + 2];
        float d3 = acc[18 + 4 * a + 3] + breg[4 * a + 3];

        int ai = a / 3, si = a % 3;
        float wsz = sqrtf(256.0f / ASP[ai]) * SCL[si];
        float hsz = sqrtf(256.0f * ASP[ai]) * SCL[si];
        float sx = (float)x * 16.0f, sy = (float)y * 16.0f;
        float x1a = sx + (7.5f - 0.5f * (wsz - 1.0f));
        float y1a = sy + (7.5f - 0.5f * (hsz - 1.0f));
        float x2a = sx + (7.5f + 0.5f * (wsz - 1.0f));
        float y2a = sy + (7.5f + 0.5f * (hsz - 1.0f));

        float wa = x2a - x1a + 1.0f, ha = y2a - y1a + 1.0f;
        float cxa = x1a + 0.5f * wa, cya = y1a + 0.5f * ha;
        float cx = d0 * wa + cxa, cy = d1 * ha + cya;
        float pw = expf(d2) * wa, ph = expf(d3) * ha;
        float bx1 = cx - 0.5f * pw, by1 = cy - 0.5f * ph;
        float bx2 = cx + 0.5f * pw, by2 = cy + 0.5f * ph;

        bx1 = fminf(fmaxf(bx1, 0.0f), im_w - 1.0f);
        by1 = fminf(fmaxf(by1, 0.0f), im_h - 1.0f);
        bx2 = fminf(fmaxf(bx2, 0.0f), im_w - 1.0f);
        by2 = fminf(fmaxf(by2, 0.0f), im_h - 1.0f);

        bool ok = (bx2 - bx1 + 1.0f >= ms) && (by2 - by1 + 1.0f >= ms);
        float s = ok ? fg : -1e9f;

        unsigned u = __float_as_uint(s);
        u = (u & 0x80000000u) ? ~u : (u | 0x80000000u);
        int idx = (y * 64 + x) * 9 + a;
        keys[(size_t)b * NBOX + idx] =
            ((unsigned long long)u << 32) | (unsigned)(~(unsigned)idx);
        pbox[(size_t)b * NBOX + idx] = make_float4(bx1, by1, bx2, by2);
    }
}

// ---------------------------------------------------------------------------
// Kernel 3: per-batch top-6000 (exact, lax.top_k tie semantics) via radix
// select + LDS bitonic sort of 8192 u64 keys; gathers sorted boxes. (R1)
// ---------------------------------------------------------------------------
__global__ __launch_bounds__(1024)
void select_sort(const unsigned long long* __restrict__ keys,
                 const float4* __restrict__ pbox,
                 float4* __restrict__ sorted) {
    __shared__ unsigned long long sbuf[SORT_N];      // 64 KiB
    __shared__ unsigned hist[16][256];               // per-wave sub-hists
    __shared__ unsigned sh_prefix, sh_remaining, sh_counter;

    const int tid = threadIdx.x;
    const int b   = blockIdx.x;
    const int wv  = tid >> 6;
    const unsigned long long* kb = keys + (size_t)b * NBOX;

    if (tid == 0) { sh_prefix = 0u; sh_remaining = PRE_NMS; sh_counter = 0u; }

    // ---- radix select: find 6000th-largest score u32 (MSB-first bytes) ----
    for (int p = 3; p >= 0; --p) {
        for (int i = tid; i < 16 * 256; i += 1024) ((unsigned*)hist)[i] = 0u;
        __syncthreads();
        unsigned prefix = sh_prefix;
        unsigned pmask  = (p == 3) ? 0u : (0xFFFFFFFFu << (8 * (p + 1)));
        for (int i = tid; i < NBOX; i += 1024) {
            unsigned u = (unsigned)(kb[i] >> 32);
            if ((u & pmask) == prefix)
                atomicAdd(&hist[wv][(u >> (8 * p)) & 255], 1u);
        }
        __syncthreads();
        if (tid < 256) {
            unsigned s = 0;
#pragma unroll
            for (int w2 = 0; w2 < 16; ++w2) s += hist[w2][tid];
            hist[0][tid] = s;
        }
        __syncthreads();
        if (tid == 0) {
            unsigned rem = sh_remaining;
            int v = 255;
            for (; v > 0; --v) {
                unsigned c = hist[0][v];
                if (rem <= c) break;
                rem -= c;
            }
            sh_prefix    = prefix | ((unsigned)v << (8 * p));
            sh_remaining = rem;
        }
        __syncthreads();
    }
    const unsigned thr = sh_prefix;

    // ---- compact all keys with score >= thr (wave-aggregated append) ----
    for (int i = tid; i < NBOX; i += 1024) {
        unsigned long long k = kb[i];
        bool act = ((unsigned)(k >> 32) >= thr);
        unsigned long long bal = __ballot(act);
        if (act) {
            int lane   = tid & 63;
            int leader = __ffsll(bal) - 1;
            unsigned base = 0;
            if (lane == leader) base = atomicAdd(&sh_counter, (unsigned)__popcll(bal));
            base = __shfl(base, leader);
            unsigned off = (unsigned)__popcll(bal & ((1ull << lane) - 1ull));
            unsigned pos2 = base + off;
            if (pos2 < SORT_N) sbuf[pos2] = k;
        }
    }
    __syncthreads();
    unsigned n = sh_counter; if (n > SORT_N) n = SORT_N;
    for (int i = (int)n + tid; i < SORT_N; i += 1024) sbuf[i] = 0ull;
    __syncthreads();

    // ---- bitonic sort, descending (keys unique: idx embedded) ----
    for (int k = 2; k <= SORT_N; k <<= 1) {
        for (int j = k >> 1; j > 0; j >>= 1) {
            for (int t = tid; t < SORT_N / 2; t += 1024) {
                int i  = ((t & ~(j - 1)) << 1) | (t & (j - 1));
                int ix = i | j;
                bool up = ((i & k) == 0);
                unsigned long long a = sbuf[i], c = sbuf[ix];
                bool sw = up ? (a < c) : (a > c);
                if (sw) { sbuf[i] = c; sbuf[ix] = a; }
            }
            __syncthreads();
        }
    }

    // ---- gather sorted boxes ----
    for (int i = tid; i < PRE_NMS; i += 1024) {
        unsigned idx = ~((unsigned)sbuf[i]);
        sorted[(size_t)b * PRE_NMS + i] = pbox[(size_t)b * NBOX + idx];
    }
}

// ---------------------------------------------------------------------------
// Kernel 4: greedy NMS over sorted boxes.  argmax == find-first-set bit. (R1)
// ---------------------------------------------------------------------------
__global__ __launch_bounds__(512, 2)
void nms(const float4* __restrict__ sorted, float* __restrict__ out) {
    __shared__ unsigned long long vmask[94];
    __shared__ int sh_j;

    const int tid = threadIdx.x;
    const int b   = blockIdx.x;
    const float4* sb = sorted + (size_t)b * PRE_NMS;

    float4 bx[12]; float ar[12];
#pragma unroll
    for (int s = 0; s < 12; ++s) {
        int i = tid + 512 * s;
        if (i < PRE_NMS) {
            float4 v = sb[i];
            bx[s] = v;
            ar[s] = (v.z - v.x + 1.0f) * (v.w - v.y + 1.0f);
        } else {
            bx[s] = make_float4(0.f, 0.f, 0.f, 0.f);
            ar[s] = 1.0f;
        }
    }
    if (tid < 94) vmask[tid] = (tid < 93) ? ~0ull : ((1ull << 48) - 1ull);
    __syncthreads();

    for (int it = 0; it < POST_NMS; ++it) {
        if (tid < 64) {
            unsigned long long w0 = vmask[tid];
            unsigned long long w1 = (tid < 30) ? vmask[tid + 64] : 0ull;
            int cand = w0 ? (tid * 64 + __ffsll(w0) - 1)
                          : (w1 ? ((tid + 64) * 64 + __ffsll(w1) - 1) : 0x7FFFFFFF);
#pragma unroll
            for (int off = 32; off > 0; off >>= 1) {
                int o = __shfl_xor(cand, off);
                cand = (o < cand) ? o : cand;
            }
            if (tid == 0) sh_j = (cand == 0x7FFFFFFF) ? 0 : cand;
        }
        __syncthreads();
        int j = sh_j;
        float4 jb = sb[j];                    // L2-hot broadcast load
        if (tid == 0) {
            float* o = out + ((size_t)b * POST_NMS + it) * 5;
            o[0] = (float)b; o[1] = jb.x; o[2] = jb.y; o[3] = jb.z; o[4] = jb.w;
        }
        float ja = (jb.z - jb.x + 1.0f) * (jb.w - jb.y + 1.0f);
#pragma unroll
        for (int s = 0; s < 12; ++s) {
            int i = tid + 512 * s;
            if (i < PRE_NMS && ((vmask[i >> 6] >> (i & 63)) & 1ull)) {
                float xx1 = fmaxf(jb.x, bx[s].x);
                float yy1 = fmaxf(jb.y, bx[s].y);
                float xx2 = fminf(jb.z, bx[s].z);
                float yy2 = fminf(jb.w, bx[s].w);
                float inter = fmaxf(0.0f, xx2 - xx1 + 1.0f) *
                              fmaxf(0.0f, yy2 - yy1 + 1.0f);
                float iou = inter / (ja + ar[s] - inter);
                if (iou > 0.7f)
                    atomicAnd(&vmask[i >> 6], ~(1ull << (i & 63)));
            }
        }
        __syncthreads();
    }
}

// ---------------------------------------------------------------------------
extern "C" void kernel_launch(void* const* d_in, const int* in_sizes, int n_in,
                              void* d_out, int out_size, void* d_ws, size_t ws_size,
                              hipStream_t stream) {
    (void)in_sizes; (void)n_in; (void)out_size; (void)ws_size;
    const float* input  = (const float*)d_in[0];
    // d_in[1] = gt_box (unused)
    const float* iminfo = (const float*)d_in[2];
    const float* wfeat  = (const float*)d_in[3];
    const float* bfeat  = (const float*)d_in[4];
    const float* wcls   = (const float*)d_in[5];
    const float* bcls   = (const float*)d_in[6];
    const float* wreg   = (const float*)d_in[7];
    const float* breg   = (const float*)d_in[8];
    float* out = (float*)d_out;

    char* ws = (char*)d_ws;
    float*               feat   = (float*)ws;                                  // 67108864 B
    unsigned long long*  keys   = (unsigned long long*)(ws + 67108864);        //  2359296 B
    float4*              pbox   = (float4*)(ws + 67108864 + 2359296);          //  4718592 B
    float4*              sorted = (float4*)(ws + 67108864 + 2359296 + 4718592);//   768000 B

    conv3x3_relu<<<dim3(8, 16, 8), 256, 0, stream>>>(input, wfeat, bfeat, feat);
    heads<<<dim3(128), 256, 0, stream>>>(feat, wcls, bcls, wreg, breg, iminfo, keys, pbox);
    select_sort<<<dim3(8), 1024, 0, stream>>>(keys, pbox, sorted);
    nms<<<dim3(8), 512, 0, stream>>>(sorted, out);
}

// Round 6
// 3280.528 us; speedup vs baseline: 3.3247x; 3.3247x over previous
//
#include <hip/hip_runtime.h>
#include <hip/hip_bf16.h>
#include <stdint.h>

#define HW      64
#define CIN     512
#define KOUT    512
#define BATCH   8
#define NANCH   9
#define NBOX    (HW*HW*NANCH)   /* 36864 */
#define PRE_NMS 6000
#define POST_NMS 300
#define SORT_N  8192

// ---------------------------------------------------------------------------
// Kernel 1: 3x3 conv (pad=1) + bias + ReLU.  fp32 vector-FMA implicit GEMM.
// WG tile: 4 rows x 64 cols x 64 out-channels.  Per-thread: 2x4 px x 8 ch.
// Per-output accumulation order (ci-major, dy, dx, serial fp32 fmaf) is
// BIT-IDENTICAL to the round-1/round-5 passing kernels.  Changes are LDS
// layout only: transposed weights ([j][k], stride 72) so wv is 2x b128
// broadcast reads; input rows padded to 68 so iv is b128+b64.
// ---------------------------------------------------------------------------
__global__ __launch_bounds__(256, 2)
void conv3x3_relu(const float* __restrict__ in, const float* __restrict__ w,
                  const float* __restrict__ bias, float* __restrict__ feat) {
    __shared__ float s_in[8][6][68];   // 8 ci, rows y0-1..y0+4, cols -1..64 (+2 pad)
    __shared__ float s_w3[72 * 72];    // [j=ci*9+tap][k], row stride 72

    const int tid = threadIdx.x;
    const int k0  = blockIdx.x * 64;
    const int y0  = blockIdx.y * 4;
    const int b   = blockIdx.z;
    const int kg  = tid & 7;          // 8 channel groups of 8
    const int pos = tid >> 3;         // 0..31
    const int tx  = pos & 15;         // x0 = tx*4
    const int ty  = pos >> 4;         // rows ty*2, ty*2+1
    const int x0  = tx * 4;

    float acc[2][8][4];
#pragma unroll
    for (int r = 0; r < 2; ++r)
#pragma unroll
        for (int k = 0; k < 8; ++k)
#pragma unroll
            for (int c = 0; c < 4; ++c) acc[r][k][c] = 0.0f;

    for (int cc = 0; cc < CIN; cc += 8) {
        __syncthreads();
        // stage input (zero-padded halo); contiguous writes, coalesced reads
        for (int i = tid; i < 8 * 6 * 66; i += 256) {
            int ci = i / 396; int rem = i % 396;
            int r = rem / 66; int col = rem % 66;
            int gx = col - 1; int gy = y0 - 1 + r;
            float v = 0.0f;
            if ((unsigned)gx < 64u && (unsigned)gy < 64u)
                v = in[(((size_t)b * CIN + cc + ci) * HW + gy) * HW + gx];
            s_in[ci][r][col] = v;
        }
        // stage weights transposed: global [k][j] (coalesced) -> LDS [j][k]
        // (write conflicts 4-way: (72j+k)%32 = (8j+k)%32 — cheap)
        for (int i = tid; i < 64 * 72; i += 256) {
            int k = i / 72; int j = i % 72;
            s_w3[j * 72 + k] = w[(size_t)(k0 + k) * (CIN * 9) + cc * 9 + j];
        }
        __syncthreads();

#pragma unroll
        for (int ci = 0; ci < 8; ++ci) {
#pragma unroll
            for (int dy = 0; dy < 3; ++dy) {
                float iv[2][6];
#pragma unroll
                for (int rr = 0; rr < 2; ++rr) {
                    int r = ty * 2 + rr + dy;
                    float4 va = *(const float4*)&s_in[ci][r][x0];       // 16B aligned
                    float2 vb = *(const float2*)&s_in[ci][r][x0 + 4];   // 8B aligned
                    iv[rr][0] = va.x; iv[rr][1] = va.y; iv[rr][2] = va.z;
                    iv[rr][3] = va.w; iv[rr][4] = vb.x; iv[rr][5] = vb.y;
                }
#pragma unroll
                for (int dx = 0; dx < 3; ++dx) {
                    const float* wp = &s_w3[(ci * 9 + dy * 3 + dx) * 72 + kg * 8];
                    float4 w0v = *(const float4*)wp;        // broadcast b128
                    float4 w1v = *(const float4*)(wp + 4);
                    float wv[8] = {w0v.x, w0v.y, w0v.z, w0v.w,
                                   w1v.x, w1v.y, w1v.z, w1v.w};
#pragma unroll
                    for (int rr = 0; rr < 2; ++rr)
#pragma unroll
                        for (int k = 0; k < 8; ++k)
#pragma unroll
                            for (int c = 0; c < 4; ++c)
                                acc[rr][k][c] = fmaf(iv[rr][dx + c], wv[k], acc[rr][k][c]);
                }
            }
        }
    }
    // bias + relu + store (float4 over x) — identical to R1
#pragma unroll
    for (int k = 0; k < 8; ++k) {
        float bv = bias[k0 + kg * 8 + k];
#pragma unroll
        for (int rr = 0; rr < 2; ++rr) {
            int y = y0 + ty * 2 + rr;
            float4 o;
            o.x = fmaxf(acc[rr][k][0] + bv, 0.0f);
            o.y = fmaxf(acc[rr][k][1] + bv, 0.0f);
            o.z = fmaxf(acc[rr][k][2] + bv, 0.0f);
            o.w = fmaxf(acc[rr][k][3] + bv, 0.0f);
            *(float4*)&feat[(((size_t)b * KOUT + k0 + kg * 8 + k) * HW + y) * HW + x0] = o;
        }
    }
}

// ---------------------------------------------------------------------------
// Kernel 2: 1x1 cls+reg heads fused with softmax, box decode, clip, min-size
// filter and sortable-key packing.  One thread per pixel.  (R1 verbatim)
// ---------------------------------------------------------------------------
__global__ __launch_bounds__(256, 2)
void heads(const float* __restrict__ feat,
           const float* __restrict__ wcls, const float* __restrict__ bcls,
           const float* __restrict__ wreg, const float* __restrict__ breg,
           const float* __restrict__ iminfo,
           unsigned long long* __restrict__ keys, float4* __restrict__ pbox) {
    __shared__ float s_w[128 * 56];   // [c][j] j=0..53 (18 cls + 36 reg), pad 56

    const int tid = threadIdx.x;
    const int pix = blockIdx.x * 256 + tid;
    const int b   = pix >> 12;
    const int rem = pix & 4095;
    const int y   = rem >> 6;
    const int x   = rem & 63;

    float acc[54];
#pragma unroll
    for (int j = 0; j < 54; ++j) acc[j] = 0.0f;

    for (int cc = 0; cc < 512; cc += 128) {
        __syncthreads();
        for (int i = tid; i < 128 * 54; i += 256) {
            int j = i / 128; int cl = i % 128;
            float v = (j < 18) ? wcls[(size_t)j * 512 + cc + cl]
                               : wreg[(size_t)(j - 18) * 512 + cc + cl];
            s_w[cl * 56 + j] = v;
        }
        __syncthreads();
        for (int c2 = 0; c2 < 128; ++c2) {
            float f = feat[(((size_t)b * 512 + cc + c2) * 64 + y) * 64 + x];
#pragma unroll
            for (int j = 0; j < 54; ++j)
                acc[j] = fmaf(f, s_w[c2 * 56 + j], acc[j]);
        }
    }

    const float im_h = iminfo[b * 3 + 0];
    const float im_w = iminfo[b * 3 + 1];
    const float ms   = 16.0f * iminfo[b * 3 + 2];
    const float ASP[3] = {0.5f, 1.0f, 2.0f};
    const float SCL[3] = {8.0f, 16.0f, 32.0f};

#pragma unroll
    for (int a = 0; a < 9; ++a) {
        float c0 = acc[2 * a]     + bcls[2 * a];
        float c1 = acc[2 * a + 1] + bcls[2 * a + 1];
        float m  = fmaxf(c0, c1);
        float e0 = expf(c0 - m), e1 = expf(c1 - m);
        float fg = e1 / (e0 + e1);

        float d0 = acc[18 + 4 * a + 0] + breg[4 * a + 0];
        float d1 = acc[18 + 4 * a + 1] + breg[4 * a + 1];
        float d2 = acc[18 + 4 * a + 2] + breg[4 * a + 2];
        float d3 = acc[18 + 4 * a + 3] + breg[4 * a + 3];

        int ai = a / 3, si = a % 3;
        float wsz = sqrtf(256.0f / ASP[ai]) * SCL[si];
        float hsz = sqrtf(256.0f * ASP[ai]) * SCL[si];
        float sx = (float)x * 16.0f, sy = (float)y * 16.0f;
        float x1a = sx + (7.5f - 0.5f * (wsz - 1.0f));
        float y1a = sy + (7.5f - 0.5f * (hsz - 1.0f));
        float x2a = sx + (7.5f + 0.5f * (wsz - 1.0f));
        float y2a = sy + (7.5f + 0.5f * (hsz - 1.0f));

        float wa = x2a - x1a + 1.0f, ha = y2a - y1a + 1.0f;
        float cxa = x1a + 0.5f * wa, cya = y1a + 0.5f * ha;
        float cx = d0 * wa + cxa, cy = d1 * ha + cya;
        float pw = expf(d2) * wa, ph = expf(d3) * ha;
        float bx1 = cx - 0.5f * pw, by1 = cy - 0.5f * ph;
        float bx2 = cx + 0.5f * pw, by2 = cy + 0.5f * ph;

        bx1 = fminf(fmaxf(bx1, 0.0f), im_w - 1.0f);
        by1 = fminf(fmaxf(by1, 0.0f), im_h - 1.0f);
        bx2 = fminf(fmaxf(bx2, 0.0f), im_w - 1.0f);
        by2 = fminf(fmaxf(by2, 0.0f), im_h - 1.0f);

        bool ok = (bx2 - bx1 + 1.0f >= ms) && (by2 - by1 + 1.0f >= ms);
        float s = ok ? fg : -1e9f;

        unsigned u = __float_as_uint(s);
        u = (u & 0x80000000u) ? ~u : (u | 0x80000000u);
        int idx = (y * 64 + x) * 9 + a;
        keys[(size_t)b * NBOX + idx] =
            ((unsigned long long)u << 32) | (unsigned)(~(unsigned)idx);
        pbox[(size_t)b * NBOX + idx] = make_float4(bx1, by1, bx2, by2);
    }
}

// ---------------------------------------------------------------------------
// Kernel 3: per-batch top-6000 (exact, lax.top_k tie semantics) via radix
// select + LDS bitonic sort of 8192 u64 keys; gathers sorted boxes. (R1)
// ---------------------------------------------------------------------------
__global__ __launch_bounds__(1024)
void select_sort(const unsigned long long* __restrict__ keys,
                 const float4* __restrict__ pbox,
                 float4* __restrict__ sorted) {
    __shared__ unsigned long long sbuf[SORT_N];      // 64 KiB
    __shared__ unsigned hist[16][256];               // per-wave sub-hists
    __shared__ unsigned sh_prefix, sh_remaining, sh_counter;

    const int tid = threadIdx.x;
    const int b   = blockIdx.x;
    const int wv  = tid >> 6;
    const unsigned long long* kb = keys + (size_t)b * NBOX;

    if (tid == 0) { sh_prefix = 0u; sh_remaining = PRE_NMS; sh_counter = 0u; }

    // ---- radix select: find 6000th-largest score u32 (MSB-first bytes) ----
    for (int p = 3; p >= 0; --p) {
        for (int i = tid; i < 16 * 256; i += 1024) ((unsigned*)hist)[i] = 0u;
        __syncthreads();
        unsigned prefix = sh_prefix;
        unsigned pmask  = (p == 3) ? 0u : (0xFFFFFFFFu << (8 * (p + 1)));
        for (int i = tid; i < NBOX; i += 1024) {
            unsigned u = (unsigned)(kb[i] >> 32);
            if ((u & pmask) == prefix)
                atomicAdd(&hist[wv][(u >> (8 * p)) & 255], 1u);
        }
        __syncthreads();
        if (tid < 256) {
            unsigned s = 0;
#pragma unroll
            for (int w2 = 0; w2 < 16; ++w2) s += hist[w2][tid];
            hist[0][tid] = s;
        }
        __syncthreads();
        if (tid == 0) {
            unsigned rem = sh_remaining;
            int v = 255;
            for (; v > 0; --v) {
                unsigned c = hist[0][v];
                if (rem <= c) break;
                rem -= c;
            }
            sh_prefix    = prefix | ((unsigned)v << (8 * p));
            sh_remaining = rem;
        }
        __syncthreads();
    }
    const unsigned thr = sh_prefix;

    // ---- compact all keys with score >= thr (wave-aggregated append) ----
    for (int i = tid; i < NBOX; i += 1024) {
        unsigned long long k = kb[i];
        bool act = ((unsigned)(k >> 32) >= thr);
        unsigned long long bal = __ballot(act);
        if (act) {
            int lane   = tid & 63;
            int leader = __ffsll(bal) - 1;
            unsigned base = 0;
            if (lane == leader) base = atomicAdd(&sh_counter, (unsigned)__popcll(bal));
            base = __shfl(base, leader);
            unsigned off = (unsigned)__popcll(bal & ((1ull << lane) - 1ull));
            unsigned pos2 = base + off;
            if (pos2 < SORT_N) sbuf[pos2] = k;
        }
    }
    __syncthreads();
    unsigned n = sh_counter; if (n > SORT_N) n = SORT_N;
    for (int i = (int)n + tid; i < SORT_N; i += 1024) sbuf[i] = 0ull;
    __syncthreads();

    // ---- bitonic sort, descending (keys unique: idx embedded) ----
    for (int k = 2; k <= SORT_N; k <<= 1) {
        for (int j = k >> 1; j > 0; j >>= 1) {
            for (int t = tid; t < SORT_N / 2; t += 1024) {
                int i  = ((t & ~(j - 1)) << 1) | (t & (j - 1));
                int ix = i | j;
                bool up = ((i & k) == 0);
                unsigned long long a = sbuf[i], c = sbuf[ix];
                bool sw = up ? (a < c) : (a > c);
                if (sw) { sbuf[i] = c; sbuf[ix] = a; }
            }
            __syncthreads();
        }
    }

    // ---- gather sorted boxes ----
    for (int i = tid; i < PRE_NMS; i += 1024) {
        unsigned idx = ~((unsigned)sbuf[i]);
        sorted[(size_t)b * PRE_NMS + i] = pbox[(size_t)b * NBOX + idx];
    }
}

// ---------------------------------------------------------------------------
// Kernel 4: greedy NMS over sorted boxes.  argmax == find-first-set bit. (R1)
// ---------------------------------------------------------------------------
__global__ __launch_bounds__(512, 2)
void nms(const float4* __restrict__ sorted, float* __restrict__ out) {
    __shared__ unsigned long long vmask[94];
    __shared__ int sh_j;

    const int tid = threadIdx.x;
    const int b   = blockIdx.x;
    const float4* sb = sorted + (size_t)b * PRE_NMS;

    float4 bx[12]; float ar[12];
#pragma unroll
    for (int s = 0; s < 12; ++s) {
        int i = tid + 512 * s;
        if (i < PRE_NMS) {
            float4 v = sb[i];
            bx[s] = v;
            ar[s] = (v.z - v.x + 1.0f) * (v.w - v.y + 1.0f);
        } else {
            bx[s] = make_float4(0.f, 0.f, 0.f, 0.f);
            ar[s] = 1.0f;
        }
    }
    if (tid < 94) vmask[tid] = (tid < 93) ? ~0ull : ((1ull << 48) - 1ull);
    __syncthreads();

    for (int it = 0; it < POST_NMS; ++it) {
        if (tid < 64) {
            unsigned long long w0 = vmask[tid];
            unsigned long long w1 = (tid < 30) ? vmask[tid + 64] : 0ull;
            int cand = w0 ? (tid * 64 + __ffsll(w0) - 1)
                          : (w1 ? ((tid + 64) * 64 + __ffsll(w1) - 1) : 0x7FFFFFFF);
#pragma unroll
            for (int off = 32; off > 0; off >>= 1) {
                int o = __shfl_xor(cand, off);
                cand = (o < cand) ? o : cand;
            }
            if (tid == 0) sh_j = (cand == 0x7FFFFFFF) ? 0 : cand;
        }
        __syncthreads();
        int j = sh_j;
        float4 jb = sb[j];                    // L2-hot broadcast load
        if (tid == 0) {
            float* o = out + ((size_t)b * POST_NMS + it) * 5;
            o[0] = (float)b; o[1] = jb.x; o[2] = jb.y; o[3] = jb.z; o[4] = jb.w;
        }
        float ja = (jb.z - jb.x + 1.0f) * (jb.w - jb.y + 1.0f);
#pragma unroll
        for (int s = 0; s < 12; ++s) {
            int i = tid + 512 * s;
            if (i < PRE_NMS && ((vmask[i >> 6] >> (i & 63)) & 1ull)) {
                float xx1 = fmaxf(jb.x, bx[s].x);
                float yy1 = fmaxf(jb.y, bx[s].y);
                float xx2 = fminf(jb.z, bx[s].z);
                float yy2 = fminf(jb.w, bx[s].w);
                float inter = fmaxf(0.0f, xx2 - xx1 + 1.0f) *
                              fmaxf(0.0f, yy2 - yy1 + 1.0f);
                float iou = inter / (ja + ar[s] - inter);
                if (iou > 0.7f)
                    atomicAnd(&vmask[i >> 6], ~(1ull << (i & 63)));
            }
        }
        __syncthreads();
    }
}

// ---------------------------------------------------------------------------
extern "C" void kernel_launch(void* const* d_in, const int* in_sizes, int n_in,
                              void* d_out, int out_size, void* d_ws, size_t ws_size,
                              hipStream_t stream) {
    (void)in_sizes; (void)n_in; (void)out_size; (void)ws_size;
    const float* input  = (const float*)d_in[0];
    // d_in[1] = gt_box (unused)
    const float* iminfo = (const float*)d_in[2];
    const float* wfeat  = (const float*)d_in[3];
    const float* bfeat  = (const float*)d_in[4];
    const float* wcls   = (const float*)d_in[5];
    const float* bcls   = (const float*)d_in[6];
    const float* wreg   = (const float*)d_in[7];
    const float* breg   = (const float*)d_in[8];
    float* out = (float*)d_out;

    char* ws = (char*)d_ws;
    float*               feat   = (float*)ws;                                  // 67108864 B
    unsigned long long*  keys   = (unsigned long long*)(ws + 67108864);        //  2359296 B
    float4*              pbox   = (float4*)(ws + 67108864 + 2359296);          //  4718592 B
    float4*              sorted = (float4*)(ws + 67108864 + 2359296 + 4718592);//   768000 B

    conv3x3_relu<<<dim3(8, 16, 8), 256, 0, stream>>>(input, wfeat, bfeat, feat);
    heads<<<dim3(128), 256, 0, stream>>>(feat, wcls, bcls, wreg, breg, iminfo, keys, pbox);
    select_sort<<<dim3(8), 1024, 0, stream>>>(keys, pbox, sorted);
    nms<<<dim3(8), 512, 0, stream>>>(sorted, out);
}

// Round 7
// 3176.883 us; speedup vs baseline: 3.4332x; 1.0326x over previous
//
#include <hip/hip_runtime.h>
#include <hip/hip_bf16.h>
#include <stdint.h>

#define HW      64
#define CIN     512
#define KOUT    512
#define BATCH   8
#define NANCH   9
#define NBOX    (HW*HW*NANCH)   /* 36864 */
#define PRE_NMS 6000
#define POST_NMS 300
#define SORT_N  8192

// ---------------------------------------------------------------------------
// Kernel 1: 3x3 conv (pad=1) + bias + ReLU.  fp32 vector-FMA implicit GEMM.
// WG tile: 4 rows x 64 cols x 64 out-channels.  Per-thread: 2x4 px x 8 ch.
// Per-output accumulation order (ci-major, dy, dx, serial fp32 fmaf) is
// BIT-IDENTICAL to R1/R6 passing kernels.  This round: double-buffered LDS,
// register prefetch (3x float4 input + 5x float4 weights), loop-invariant
// staging descriptors, ONE barrier per chunk.  LDS cell values unchanged
// (halo cells are always zero -> zeroed once, interior staged per chunk).
// ---------------------------------------------------------------------------
__global__ __launch_bounds__(256, 2)
void conv3x3_relu(const float* __restrict__ in, const float* __restrict__ w,
                  const float* __restrict__ bias, float* __restrict__ feat) {
    __shared__ float s_in[2][8][6][68];   // [buf][ci][r][col]; col = gx+1; pads 0
    __shared__ float s_w3[2][72 * 72];    // [buf][j=ci*9+tap][k], stride 72

    const int tid = threadIdx.x;
    const int k0  = blockIdx.x * 64;
    const int y0  = blockIdx.y * 4;
    const int b   = blockIdx.z;
    const int kg  = tid & 7;          // 8 channel groups of 8
    const int pos = tid >> 3;         // 0..31
    const int tx  = pos & 15;         // x0 = tx*4
    const int ty  = pos >> 4;         // rows ty*2, ty*2+1
    const int x0  = tx * 4;

    // ---- loop-invariant staging descriptors ----
    // input: 3 float4 slots over 8ci x 6r x 16c4 (interior cols only)
    int in_lds[3]; int in_goff[3]; bool in_ok[3];
#pragma unroll
    for (int s = 0; s < 3; ++s) {
        int v  = tid + 256 * s;           // 0..767
        int ci = v / 96, rem = v % 96;
        int r  = rem >> 4, c4 = rem & 15;
        int gy = y0 - 1 + r;
        in_ok[s]  = ((unsigned)gy < 64u);
        int gyc   = gy < 0 ? 0 : (gy > 63 ? 63 : gy);
        in_lds[s] = (ci * 6 + r) * 68 + 1 + 4 * c4;
        in_goff[s] = ((b * 512 + ci) * 64 + gyc) * 64 + 4 * c4;  // + ch*4096
    }
    // weights: 5 float4 slots over 1152 q = k*18 + j4 (slot 4 ragged)
    int w_lds[5]; int w_goff[5]; bool w_ok[5];
#pragma unroll
    for (int s = 0; s < 5; ++s) {
        int q = tid + 256 * s;
        w_ok[s] = (q < 1152);
        int qq = w_ok[s] ? q : 0;
        int k = qq / 18, j4 = qq % 18;
        w_lds[s]  = (j4 * 4) * 72 + k;                 // rows j4*4..j4*4+3
        w_goff[s] = (k0 + k) * 4608 + 4 * j4;          // + ch*9
    }

    // zero both input buffers once (covers halo rows/cols; interior re-staged)
    for (int i = tid; i < 2 * 8 * 6 * 68; i += 256) ((float*)s_in)[i] = 0.0f;

    float4 pin[3], pw[5];
    auto prefetch = [&](int ch) {
#pragma unroll
        for (int s = 0; s < 3; ++s)
            pin[s] = *(const float4*)&in[in_goff[s] + ch * 4096];
#pragma unroll
        for (int s = 0; s < 5; ++s)
            pw[s] = *(const float4*)&w[w_goff[s] + ch * 9];
    };
    prefetch(0);

    float acc[2][8][4];
#pragma unroll
    for (int r = 0; r < 2; ++r)
#pragma unroll
        for (int k = 0; k < 8; ++k)
#pragma unroll
            for (int c = 0; c < 4; ++c) acc[r][k][c] = 0.0f;

    for (int cc8 = 0; cc8 < 64; ++cc8) {
        float* SIN = &s_in[cc8 & 1][0][0][0];
        float* SW  = &s_w3[cc8 & 1][0];

        // staged regs -> LDS
#pragma unroll
        for (int s = 0; s < 3; ++s) if (in_ok[s]) {
            SIN[in_lds[s] + 0] = pin[s].x;
            SIN[in_lds[s] + 1] = pin[s].y;
            SIN[in_lds[s] + 2] = pin[s].z;
            SIN[in_lds[s] + 3] = pin[s].w;
        }
#pragma unroll
        for (int s = 0; s < 5; ++s) if (w_ok[s]) {
            SW[w_lds[s] + 0 * 72] = pw[s].x;
            SW[w_lds[s] + 1 * 72] = pw[s].y;
            SW[w_lds[s] + 2 * 72] = pw[s].z;
            SW[w_lds[s] + 3 * 72] = pw[s].w;
        }
        __syncthreads();
        if (cc8 < 63) prefetch((cc8 + 1) * 8);   // latency hidden by compute

        // ---- compute: EXACT R1/R6 FMA sequence ----
#pragma unroll
        for (int ci = 0; ci < 8; ++ci) {
#pragma unroll
            for (int dy = 0; dy < 3; ++dy) {
                float iv[2][6];
#pragma unroll
                for (int rr = 0; rr < 2; ++rr) {
                    int r = ty * 2 + rr + dy;
                    const float* rowp = &SIN[(ci * 6 + r) * 68];
                    float4 va = *(const float4*)&rowp[x0];       // 16B aligned
                    float2 vb = *(const float2*)&rowp[x0 + 4];   // 8B aligned
                    iv[rr][0] = va.x; iv[rr][1] = va.y; iv[rr][2] = va.z;
                    iv[rr][3] = va.w; iv[rr][4] = vb.x; iv[rr][5] = vb.y;
                }
#pragma unroll
                for (int dx = 0; dx < 3; ++dx) {
                    const float* wp = &SW[(ci * 9 + dy * 3 + dx) * 72 + kg * 8];
                    float4 w0v = *(const float4*)wp;             // broadcast b128
                    float4 w1v = *(const float4*)(wp + 4);
                    float wv[8] = {w0v.x, w0v.y, w0v.z, w0v.w,
                                   w1v.x, w1v.y, w1v.z, w1v.w};
#pragma unroll
                    for (int rr = 0; rr < 2; ++rr)
#pragma unroll
                        for (int k = 0; k < 8; ++k)
#pragma unroll
                            for (int c = 0; c < 4; ++c)
                                acc[rr][k][c] = fmaf(iv[rr][dx + c], wv[k], acc[rr][k][c]);
                }
            }
        }
    }
    // bias + relu + store (float4 over x) — identical to R1/R6
#pragma unroll
    for (int k = 0; k < 8; ++k) {
        float bv = bias[k0 + kg * 8 + k];
#pragma unroll
        for (int rr = 0; rr < 2; ++rr) {
            int y = y0 + ty * 2 + rr;
            float4 o;
            o.x = fmaxf(acc[rr][k][0] + bv, 0.0f);
            o.y = fmaxf(acc[rr][k][1] + bv, 0.0f);
            o.z = fmaxf(acc[rr][k][2] + bv, 0.0f);
            o.w = fmaxf(acc[rr][k][3] + bv, 0.0f);
            *(float4*)&feat[(((size_t)b * KOUT + k0 + kg * 8 + k) * HW + y) * HW + x0] = o;
        }
    }
}

// ---------------------------------------------------------------------------
// Kernel 2: 1x1 cls+reg heads fused with softmax, box decode, clip, min-size
// filter and sortable-key packing.  One thread per pixel.  (R1 + unroll 8)
// ---------------------------------------------------------------------------
__global__ __launch_bounds__(256, 2)
void heads(const float* __restrict__ feat,
           const float* __restrict__ wcls, const float* __restrict__ bcls,
           const float* __restrict__ wreg, const float* __restrict__ breg,
           const float* __restrict__ iminfo,
           unsigned long long* __restrict__ keys, float4* __restrict__ pbox) {
    __shared__ float s_w[128 * 56];   // [c][j] j=0..53 (18 cls + 36 reg), pad 56

    const int tid = threadIdx.x;
    const int pix = blockIdx.x * 256 + tid;
    const int b   = pix >> 12;
    const int rem = pix & 4095;
    const int y   = rem >> 6;
    const int x   = rem & 63;

    float acc[54];
#pragma unroll
    for (int j = 0; j < 54; ++j) acc[j] = 0.0f;

    for (int cc = 0; cc < 512; cc += 128) {
        __syncthreads();
        for (int i = tid; i < 128 * 54; i += 256) {
            int j = i / 128; int cl = i % 128;
            float v = (j < 18) ? wcls[(size_t)j * 512 + cc + cl]
                               : wreg[(size_t)(j - 18) * 512 + cc + cl];
            s_w[cl * 56 + j] = v;
        }
        __syncthreads();
#pragma unroll 8
        for (int c2 = 0; c2 < 128; ++c2) {
            float f = feat[(((size_t)b * 512 + cc + c2) * 64 + y) * 64 + x];
#pragma unroll
            for (int j = 0; j < 54; ++j)
                acc[j] = fmaf(f, s_w[c2 * 56 + j], acc[j]);
        }
    }

    const float im_h = iminfo[b * 3 + 0];
    const float im_w = iminfo[b * 3 + 1];
    const float ms   = 16.0f * iminfo[b * 3 + 2];
    const float ASP[3] = {0.5f, 1.0f, 2.0f};
    const float SCL[3] = {8.0f, 16.0f, 32.0f};

#pragma unroll
    for (int a = 0; a < 9; ++a) {
        float c0 = acc[2 * a]     + bcls[2 * a];
        float c1 = acc[2 * a + 1] + bcls[2 * a + 1];
        float m  = fmaxf(c0, c1);
        float e0 = expf(c0 - m), e1 = expf(c1 - m);
        float fg = e1 / (e0 + e1);

        float d0 = acc[18 + 4 * a + 0] + breg[4 * a + 0];
        float d1 = acc[18 + 4 * a + 1] + breg[4 * a + 1];
        float d2 = acc[18 + 4 * a + 2] + breg[4 * a + 2];
        float d3 = acc[18 + 4 * a + 3] + breg[4 * a + 3];

        int ai = a / 3, si = a % 3;
        float wsz = sqrtf(256.0f / ASP[ai]) * SCL[si];
        float hsz = sqrtf(256.0f * ASP[ai]) * SCL[si];
        float sx = (float)x * 16.0f, sy = (float)y * 16.0f;
        float x1a = sx + (7.5f - 0.5f * (wsz - 1.0f));
        float y1a = sy + (7.5f - 0.5f * (hsz - 1.0f));
        float x2a = sx + (7.5f + 0.5f * (wsz - 1.0f));
        float y2a = sy + (7.5f + 0.5f * (hsz - 1.0f));

        float wa = x2a - x1a + 1.0f, ha = y2a - y1a + 1.0f;
        float cxa = x1a + 0.5f * wa, cya = y1a + 0.5f * ha;
        float cx = d0 * wa + cxa, cy = d1 * ha + cya;
        float pw = expf(d2) * wa, ph = expf(d3) * ha;
        float bx1 = cx - 0.5f * pw, by1 = cy - 0.5f * ph;
        float bx2 = cx + 0.5f * pw, by2 = cy + 0.5f * ph;

        bx1 = fminf(fmaxf(bx1, 0.0f), im_w - 1.0f);
        by1 = fminf(fmaxf(by1, 0.0f), im_h - 1.0f);
        bx2 = fminf(fmaxf(bx2, 0.0f), im_w - 1.0f);
        by2 = fminf(fmaxf(by2, 0.0f), im_h - 1.0f);

        bool ok = (bx2 - bx1 + 1.0f >= ms) && (by2 - by1 + 1.0f >= ms);
        float s = ok ? fg : -1e9f;

        unsigned u = __float_as_uint(s);
        u = (u & 0x80000000u) ? ~u : (u | 0x80000000u);
        int idx = (y * 64 + x) * 9 + a;
        keys[(size_t)b * NBOX + idx] =
            ((unsigned long long)u << 32) | (unsigned)(~(unsigned)idx);
        pbox[(size_t)b * NBOX + idx] = make_float4(bx1, by1, bx2, by2);
    }
}

// ---------------------------------------------------------------------------
// Kernel 3: per-batch top-6000 (exact, lax.top_k tie semantics) via radix
// select + LDS bitonic sort of 8192 u64 keys; gathers sorted boxes. (R1)
// ---------------------------------------------------------------------------
__global__ __launch_bounds__(1024)
void select_sort(const unsigned long long* __restrict__ keys,
                 const float4* __restrict__ pbox,
                 float4* __restrict__ sorted) {
    __shared__ unsigned long long sbuf[SORT_N];      // 64 KiB
    __shared__ unsigned hist[16][256];               // per-wave sub-hists
    __shared__ unsigned sh_prefix, sh_remaining, sh_counter;

    const int tid = threadIdx.x;
    const int b   = blockIdx.x;
    const int wv  = tid >> 6;
    const unsigned long long* kb = keys + (size_t)b * NBOX;

    if (tid == 0) { sh_prefix = 0u; sh_remaining = PRE_NMS; sh_counter = 0u; }

    // ---- radix select: find 6000th-largest score u32 (MSB-first bytes) ----
    for (int p = 3; p >= 0; --p) {
        for (int i = tid; i < 16 * 256; i += 1024) ((unsigned*)hist)[i] = 0u;
        __syncthreads();
        unsigned prefix = sh_prefix;
        unsigned pmask  = (p == 3) ? 0u : (0xFFFFFFFFu << (8 * (p + 1)));
        for (int i = tid; i < NBOX; i += 1024) {
            unsigned u = (unsigned)(kb[i] >> 32);
            if ((u & pmask) == prefix)
                atomicAdd(&hist[wv][(u >> (8 * p)) & 255], 1u);
        }
        __syncthreads();
        if (tid < 256) {
            unsigned s = 0;
#pragma unroll
            for (int w2 = 0; w2 < 16; ++w2) s += hist[w2][tid];
            hist[0][tid] = s;
        }
        __syncthreads();
        if (tid == 0) {
            unsigned rem = sh_remaining;
            int v = 255;
            for (; v > 0; --v) {
                unsigned c = hist[0][v];
                if (rem <= c) break;
                rem -= c;
            }
            sh_prefix    = prefix | ((unsigned)v << (8 * p));
            sh_remaining = rem;
        }
        __syncthreads();
    }
    const unsigned thr = sh_prefix;

    // ---- compact all keys with score >= thr (wave-aggregated append) ----
    for (int i = tid; i < NBOX; i += 1024) {
        unsigned long long k = kb[i];
        bool act = ((unsigned)(k >> 32) >= thr);
        unsigned long long bal = __ballot(act);
        if (act) {
            int lane   = tid & 63;
            int leader = __ffsll(bal) - 1;
            unsigned base = 0;
            if (lane == leader) base = atomicAdd(&sh_counter, (unsigned)__popcll(bal));
            base = __shfl(base, leader);
            unsigned off = (unsigned)__popcll(bal & ((1ull << lane) - 1ull));
            unsigned pos2 = base + off;
            if (pos2 < SORT_N) sbuf[pos2] = k;
        }
    }
    __syncthreads();
    unsigned n = sh_counter; if (n > SORT_N) n = SORT_N;
    for (int i = (int)n + tid; i < SORT_N; i += 1024) sbuf[i] = 0ull;
    __syncthreads();

    // ---- bitonic sort, descending (keys unique: idx embedded) ----
    for (int k = 2; k <= SORT_N; k <<= 1) {
        for (int j = k >> 1; j > 0; j >>= 1) {
            for (int t = tid; t < SORT_N / 2; t += 1024) {
                int i  = ((t & ~(j - 1)) << 1) | (t & (j - 1));
                int ix = i | j;
                bool up = ((i & k) == 0);
                unsigned long long a = sbuf[i], c = sbuf[ix];
                bool sw = up ? (a < c) : (a > c);
                if (sw) { sbuf[i] = c; sbuf[ix] = a; }
            }
            __syncthreads();
        }
    }

    // ---- gather sorted boxes ----
    for (int i = tid; i < PRE_NMS; i += 1024) {
        unsigned idx = ~((unsigned)sbuf[i]);
        sorted[(size_t)b * PRE_NMS + i] = pbox[(size_t)b * NBOX + idx];
    }
}

// ---------------------------------------------------------------------------
// Kernel 4: greedy NMS over sorted boxes.  argmax == find-first-set bit. (R1)
// ---------------------------------------------------------------------------
__global__ __launch_bounds__(512, 2)
void nms(const float4* __restrict__ sorted, float* __restrict__ out) {
    __shared__ unsigned long long vmask[94];
    __shared__ int sh_j;

    const int tid = threadIdx.x;
    const int b   = blockIdx.x;
    const float4* sb = sorted + (size_t)b * PRE_NMS;

    float4 bx[12]; float ar[12];
#pragma unroll
    for (int s = 0; s < 12; ++s) {
        int i = tid + 512 * s;
        if (i < PRE_NMS) {
            float4 v = sb[i];
            bx[s] = v;
            ar[s] = (v.z - v.x + 1.0f) * (v.w - v.y + 1.0f);
        } else {
            bx[s] = make_float4(0.f, 0.f, 0.f, 0.f);
            ar[s] = 1.0f;
        }
    }
    if (tid < 94) vmask[tid] = (tid < 93) ? ~0ull : ((1ull << 48) - 1ull);
    __syncthreads();

    for (int it = 0; it < POST_NMS; ++it) {
        if (tid < 64) {
            unsigned long long w0 = vmask[tid];
            unsigned long long w1 = (tid < 30) ? vmask[tid + 64] : 0ull;
            int cand = w0 ? (tid * 64 + __ffsll(w0) - 1)
                          : (w1 ? ((tid + 64) * 64 + __ffsll(w1) - 1) : 0x7FFFFFFF);
#pragma unroll
            for (int off = 32; off > 0; off >>= 1) {
                int o = __shfl_xor(cand, off);
                cand = (o < cand) ? o : cand;
            }
            if (tid == 0) sh_j = (cand == 0x7FFFFFFF) ? 0 : cand;
        }
        __syncthreads();
        int j = sh_j;
        float4 jb = sb[j];                    // L2-hot broadcast load
        if (tid == 0) {
            float* o = out + ((size_t)b * POST_NMS + it) * 5;
            o[0] = (float)b; o[1] = jb.x; o[2] = jb.y; o[3] = jb.z; o[4] = jb.w;
        }
        float ja = (jb.z - jb.x + 1.0f) * (jb.w - jb.y + 1.0f);
#pragma unroll
        for (int s = 0; s < 12; ++s) {
            int i = tid + 512 * s;
            if (i < PRE_NMS && ((vmask[i >> 6] >> (i & 63)) & 1ull)) {
                float xx1 = fmaxf(jb.x, bx[s].x);
                float yy1 = fmaxf(jb.y, bx[s].y);
                float xx2 = fminf(jb.z, bx[s].z);
                float yy2 = fminf(jb.w, bx[s].w);
                float inter = fmaxf(0.0f, xx2 - xx1 + 1.0f) *
                              fmaxf(0.0f, yy2 - yy1 + 1.0f);
                float iou = inter / (ja + ar[s] - inter);
                if (iou > 0.7f)
                    atomicAnd(&vmask[i >> 6], ~(1ull << (i & 63)));
            }
        }
        __syncthreads();
    }
}

// ---------------------------------------------------------------------------
extern "C" void kernel_launch(void* const* d_in, const int* in_sizes, int n_in,
                              void* d_out, int out_size, void* d_ws, size_t ws_size,
                              hipStream_t stream) {
    (void)in_sizes; (void)n_in; (void)out_size; (void)ws_size;
    const float* input  = (const float*)d_in[0];
    // d_in[1] = gt_box (unused)
    const float* iminfo = (const float*)d_in[2];
    const float* wfeat  = (const float*)d_in[3];
    const float* bfeat  = (const float*)d_in[4];
    const float* wcls   = (const float*)d_in[5];
    const float* bcls   = (const float*)d_in[6];
    const float* wreg   = (const float*)d_in[7];
    const float* breg   = (const float*)d_in[8];
    float* out = (float*)d_out;

    char* ws = (char*)d_ws;
    float*               feat   = (float*)ws;                                  // 67108864 B
    unsigned long long*  keys   = (unsigned long long*)(ws + 67108864);        //  2359296 B
    float4*              pbox   = (float4*)(ws + 67108864 + 2359296);          //  4718592 B
    float4*              sorted = (float4*)(ws + 67108864 + 2359296 + 4718592);//   768000 B

    conv3x3_relu<<<dim3(8, 16, 8), 256, 0, stream>>>(input, wfeat, bfeat, feat);
    heads<<<dim3(128), 256, 0, stream>>>(feat, wcls, bcls, wreg, breg, iminfo, keys, pbox);
    select_sort<<<dim3(8), 1024, 0, stream>>>(keys, pbox, sorted);
    nms<<<dim3(8), 512, 0, stream>>>(sorted, out);
}